// Round 11
// baseline (101.675 us; speedup 1.0000x reference)
//
#include <hip/hip_runtime.h>
#include <math.h>

#define BQ 8192
#define HD 1024
#define NE 8
#define CAP 1280

#define BM 128
#define BN 256
#define BK 64
#define NKT 16           // K tiles
#define NRT 10           // row tiles per expert (CAP/BM)
#define NCT 4            // col tiles (HD/BN)

// ---------------- workspace layout (bytes) ----------------
#define WS_CURSOR   0           // int[NE]
#define WS_S        64          // float[NE]
#define WS_ZSUM     96          // float
#define WS_CESUM    100         // float
#define WS_ROWLIST  128         // int[NE*CAP] -> ends 41088
#define WS_LOGITS2  41088       // float[NE*CAP*2] -> ends 123008
#define WS_HEAD     123008      // memset size
#define WS_XC       123008      // bf16 xc [NE][CAP][HD] = 20971520
#define WS_W1T      21094528    // bf16 w1^T [NE][n][k] = 16777216

using f32x4  = __attribute__((ext_vector_type(4))) float;
using bf16x8 = __attribute__((ext_vector_type(8))) __bf16;

__device__ __forceinline__ float gelu_exact(float v) {
    return 0.5f * v * (1.0f + erff(v * 0.70710678118654752440f));
}

__device__ __forceinline__ unsigned short f2bf(float f) {
    union { float f; unsigned int u; } v; v.f = f;
    unsigned int u = v.u;
    unsigned int r = (u + 0x7FFFu + ((u >> 16) & 1u)) >> 16;
    return (unsigned short)r;
}

__device__ __forceinline__ void gll16(const void* g, void* l) {
    __builtin_amdgcn_global_load_lds((const __attribute__((address_space(1))) void*)g,
                                     (__attribute__((address_space(3))) void*)l, 16, 0, 0);
}

// ---- prep: router+compact (blocks 0..511) || w1 transpose (512..2559) -------
__global__ __launch_bounds__(256) void prep_kernel(
    const float* __restrict__ x, const float* __restrict__ gate_w,
    const float* __restrict__ w1,
    int* __restrict__ cursor, float* __restrict__ S, float* __restrict__ zsum,
    int* __restrict__ rowlist, unsigned short* __restrict__ xc,
    unsigned short* __restrict__ w1t)
{
    __shared__ __align__(16) char smem[33280];
    int tid = threadIdx.x;

    if (blockIdx.x >= 512) {
        // ---- transpose role: w1 fp32 [e][k][n] -> bf16 [e][n][k], 64x64 tile
        unsigned short (*lt)[72] = (unsigned short (*)[72])smem;
        int tile = blockIdx.x - 512;          // 0..2047
        int e = tile >> 8;
        int rem = tile & 255;
        int k0 = (rem >> 4) << 6, n0 = (rem & 15) << 6;
        const float* src = w1 + ((size_t)e << 20) + (size_t)k0 * HD + n0;
        #pragma unroll
        for (int s = 0; s < 4; s++) {
            int q = tid + s * 256;
            int kk = q >> 4, n4 = q & 15;
            float4 v = *(const float4*)(src + (size_t)kk * HD + n4 * 4);
            lt[n4 * 4 + 0][kk] = f2bf(v.x);
            lt[n4 * 4 + 1][kk] = f2bf(v.y);
            lt[n4 * 4 + 2][kk] = f2bf(v.z);
            lt[n4 * 4 + 3][kk] = f2bf(v.w);
        }
        __syncthreads();
        unsigned short* dst = w1t + ((size_t)e << 20) + (size_t)n0 * HD + k0;
        #pragma unroll
        for (int s = 0; s < 4; s++) {
            int q = tid + s * 256;
            int nn = q >> 4, kq = q & 15;
            *(ushort4*)(dst + (size_t)nn * HD + kq * 4) = *(ushort4*)&lt[nn][kq * 4];
        }
        return;
    }

    // ---- router role: rows [bid*16, bid*16+16)
    float* gw    = (float*)smem;                    // 32 KB
    float* sS    = (float*)(smem + 32768);          // 8
    float* sZ    = (float*)(smem + 32800);          // 1
    int*   sBI   = (int*)(smem + 32832);            // 16
    int*   sSlot = (int*)(smem + 32912);            // 16
    int*   sBase = (int*)(smem + 32992);            // 8

    for (int i = tid * 4; i < NE * HD; i += 256 * 4) {
        *(float4*)(gw + i) = *(const float4*)(gate_w + i);
    }
    if (tid < NE) sS[tid] = 0.f;
    if (tid == 0) sZ[0] = 0.f;
    __syncthreads();

    int wave = tid >> 6, lane = tid & 63;
    int r0 = blockIdx.x * 16;
    float accS[NE];
    #pragma unroll
    for (int e = 0; e < NE; e++) accS[e] = 0.f;
    float accZ = 0.f;

    // phase 1: logits + per-row argmax (4 rows per wave)
    #pragma unroll 1
    for (int i = 0; i < 4; i++) {
        int li = wave * 4 + i;
        int r = r0 + li;
        const float* xr = x + (size_t)r * HD;
        float acc[NE];
        #pragma unroll
        for (int e = 0; e < NE; e++) acc[e] = 0.f;
        #pragma unroll
        for (int it = 0; it < 4; it++) {
            int k = lane * 4 + it * 256;
            float4 xv = *(const float4*)(xr + k);
            #pragma unroll
            for (int e = 0; e < NE; e++) {
                const float* g = gw + e * HD + k;
                acc[e] += xv.x * g[0] + xv.y * g[1] + xv.z * g[2] + xv.w * g[3];
            }
        }
        #pragma unroll
        for (int e = 0; e < NE; e++) {
            #pragma unroll
            for (int off = 32; off > 0; off >>= 1)
                acc[e] += __shfl_xor(acc[e], off);
        }
        if (lane == 0) {
            float m = acc[0]; int bi = 0;
            #pragma unroll
            for (int e = 1; e < NE; e++) if (acc[e] > m) { m = acc[e]; bi = e; }
            float se = 0.f, ex[NE];
            #pragma unroll
            for (int e = 0; e < NE; e++) { ex[e] = expf(acc[e] - m); se += ex[e]; }
            float inv = 1.f / se;
            #pragma unroll
            for (int e = 0; e < NE; e++) accS[e] += ex[e] * inv;
            float lse = m + logf(se);
            accZ += lse * lse;
            sBI[li] = bi;
        }
    }
    if (lane == 0) {
        #pragma unroll
        for (int e = 0; e < NE; e++) atomicAdd(&sS[e], accS[e]);
        atomicAdd(sZ, accZ);
    }
    __syncthreads();

    // phase 2: block-level capacity reservation (8 atomics per block)
    if (tid < NE) {
        int cnt = 0;
        #pragma unroll
        for (int j = 0; j < 16; j++) cnt += (sBI[j] == tid);
        sBase[tid] = atomicAdd(&cursor[tid], cnt);
        atomicAdd(&S[tid], sS[tid]);
    }
    if (tid == 0) atomicAdd(zsum, sZ[0]);
    __syncthreads();

    // phase 3: per-row slot = base + rank
    if (tid < 16) {
        int bi = sBI[tid];
        int rank = 0;
        for (int j = 0; j < tid; j++) rank += (sBI[j] == bi);
        int slot = sBase[bi] + rank;
        sSlot[tid] = slot;
        if (slot < CAP) rowlist[bi * CAP + slot] = r0 + tid;
    }
    __syncthreads();

    // phase 4: re-read (hot) x rows, convert, write capacity slab
    #pragma unroll 1
    for (int i = 0; i < 4; i++) {
        int li = wave * 4 + i;
        int bi = sBI[li];
        int pos = sSlot[li];
        if (pos >= CAP) continue;
        const float* src = x + (size_t)(r0 + li) * HD;
        unsigned short* dst = xc + ((size_t)(bi * CAP + pos)) * HD;
        #pragma unroll
        for (int it = 0; it < 4; it++) {
            int k = lane * 4 + it * 256;
            float4 v = *(const float4*)(src + k);
            ushort4 o;
            o.x = f2bf(v.x); o.y = f2bf(v.y); o.z = f2bf(v.z); o.w = f2bf(v.w);
            *(ushort4*)(dst + k) = o;
        }
    }
}

// ---- MFMA expert GEMM: 8-phase-style schedule, BK=64, 3-buffer depth-2 ------
// grid 320: e = bid&7 (XCD-pinned); tix = bid>>3: col = tix/NRT, rt = tix%NRT.
// 512 thr = 8 waves (2M x 4N), wave tile 64x64, 16x16x32 MFMA.
__global__ __launch_bounds__(512) void expert_gemm_kernel(
    const unsigned short* __restrict__ xc, const unsigned short* __restrict__ w1t,
    const float* __restrict__ b1, const float* __restrict__ w2,
    const int* __restrict__ cursor, float* __restrict__ logits2c)
{
    int bid = blockIdx.x;
    int e = bid & 7;
    int tix = bid >> 3;
    int col = tix / NRT;
    int rt = tix - col * NRT;
    int cnt = cursor[e]; if (cnt > CAP) cnt = CAP;
    if (rt * BM >= cnt) return;
    int n0 = col * BN;

    // 3 x [A 16KB | B 32KB] = 144KB
    __shared__ __align__(16) char lds[3][49152];

    int t = threadIdx.x;
    int l = t & 63;

    // staging geometry: row chunkline = 128B (BK=64 bf16), 8 chunks of 16B.
    // rule-21 both-sides swizzle: chunk' = chunk ^ (row&7)
    int c7 = (t & 7) ^ ((t >> 3) & 7);            // pre-swizzled source chunk
    int mrow = t >> 3;                            // 0..63
    const char* xcp  = (const char*)xc + ((size_t)e * CAP) * 2048;
    const char* w1tp = (const char*)w1t + ((size_t)e << 21);
    const char* srcA = xcp + (size_t)(rt * BM + mrow) * 2048 + c7 * 16;   // rows mrow, mrow+64
    const char* srcB = w1tp + (size_t)(n0 + mrow) * 2048 + c7 * 16;       // rows +0,64,128,192

    int wid = t >> 6;                 // 0..7
    int wr = wid >> 2, wc = wid & 3;  // 2M x 4N, wave tile 64x64
    int r = l & 15, h = l >> 4;
    int rx = (r & 7) << 4;            // read-side swizzle XOR (bytes)

    f32x4 acc[4][4];
    #pragma unroll
    for (int i = 0; i < 4; i++)
        #pragma unroll
        for (int j = 0; j < 4; j++) acc[i][j] = (f32x4)(0.f);

    // stage part 0: A rows (2 gll) + B round 0 (1 gll); part 1: B rounds 1-3
    auto stage_p0 = [&](int kt, int buf) {
        size_t ko = (size_t)kt * 128;
        gll16(srcA + ko,              lds[buf] + t * 16);
        gll16(srcA + ko + 64 * 2048,  lds[buf] + 8192 + t * 16);
        gll16(srcB + ko,              lds[buf] + 16384 + t * 16);
    };
    auto stage_p1 = [&](int kt, int buf) {
        size_t ko = (size_t)kt * 128;
        gll16(srcB + ko + 64 * 2048,  lds[buf] + 24576 + t * 16);
        gll16(srcB + ko + 128 * 2048, lds[buf] + 32768 + t * 16);
        gll16(srcB + ko + 192 * 2048, lds[buf] + 40960 + t * 16);
    };
    // compute one k-half (16 MFMA) from buf
    auto compute = [&](int buf, int kh) {
        const char* Ar = lds[buf] + (wr * 64 + r) * 128 + (((h + 4 * kh) << 4) ^ rx);
        const char* Br = lds[buf] + 16384 + (wc * 64 + r) * 128 + (((h + 4 * kh) << 4) ^ rx);
        bf16x8 a[4], b[4];
        #pragma unroll
        for (int i = 0; i < 4; i++) {
            a[i] = *(const bf16x8*)(Ar + i * 2048);
            b[i] = *(const bf16x8*)(Br + i * 2048);
        }
        asm volatile("s_waitcnt lgkmcnt(0)" ::: "memory");
        __builtin_amdgcn_sched_barrier(0);
        __builtin_amdgcn_s_setprio(1);
        #pragma unroll
        for (int i = 0; i < 4; i++)
            #pragma unroll
            for (int j = 0; j < 4; j++)
                acc[i][j] = __builtin_amdgcn_mfma_f32_16x16x32_bf16(a[i], b[j], acc[i][j], 0, 0, 0);
        __builtin_amdgcn_s_setprio(0);
    };

    // prologue: 2 tiles in flight (12 gll)
    stage_p0(0, 0); stage_p1(0, 0);
    stage_p0(1, 1); stage_p1(1, 1);

    #pragma unroll 1
    for (int kt = 0; kt < NKT; ++kt) {
        int buf = kt % 3;
        int nbuf = (kt + 2) % 3;
        if (kt < NKT - 1) asm volatile("s_waitcnt vmcnt(6)" ::: "memory");
        else              asm volatile("s_waitcnt vmcnt(0)" ::: "memory");
        __builtin_amdgcn_s_barrier();
        // phase 0: k-half 0 + issue half of stage(kt+2)
        if (kt + 2 < NKT) stage_p0(kt + 2, nbuf);
        compute(buf, 0);
        __builtin_amdgcn_s_barrier();
        // phase 1: k-half 1 + issue rest of stage(kt+2)
        if (kt + 2 < NKT) stage_p1(kt + 2, nbuf);
        compute(buf, 1);
        __builtin_amdgcn_s_barrier();
    }

    // epilogue: bias + gelu + w2 partial dot + 16-lane reduce
    float b1v[4], w20v[4], w21v[4];
    #pragma unroll
    for (int j = 0; j < 4; j++) {
        int cj = n0 + wc * 64 + j * 16 + r;
        b1v[j]  = b1[e * HD + cj];
        w20v[j] = w2[((size_t)e * HD + cj) * 2 + 0];
        w21v[j] = w2[((size_t)e * HD + cj) * 2 + 1];
    }
    #pragma unroll
    for (int i = 0; i < 4; i++) {
        #pragma unroll
        for (int reg = 0; reg < 4; reg++) {
            float s0 = 0.f, s1 = 0.f;
            #pragma unroll
            for (int j = 0; j < 4; j++) {
                float hv = gelu_exact(acc[i][j][reg] + b1v[j]);
                s0 += hv * w20v[j];
                s1 += hv * w21v[j];
            }
            #pragma unroll
            for (int offx = 1; offx < 16; offx <<= 1) {
                s0 += __shfl_xor(s0, offx);
                s1 += __shfl_xor(s1, offx);
            }
            if (r == 0) {
                int p = rt * BM + wr * 64 + i * 16 + 4 * h + reg;
                if (p < cnt) {
                    atomicAdd(&logits2c[(e * CAP + p) * 2 + 0], s0);
                    atomicAdd(&logits2c[(e * CAP + p) * 2 + 1], s1);
                }
            }
        }
    }
}

// ---- CE over (softmaxed) expert outputs (capacity-slot order) ---------------
__global__ __launch_bounds__(256) void ce_kernel(
    const float* __restrict__ logits2c, const float* __restrict__ b2,
    const int* __restrict__ cursor, const int* __restrict__ rowlist,
    const int* __restrict__ label, float* __restrict__ cesum)
{
    __shared__ float red[4];
    int tid = threadIdx.x;
    int s = blockIdx.x * 256 + tid;     // 0..NE*CAP-1
    int e = s / CAP;
    int local = s - e * CAP;
    int cnt = cursor[e]; if (cnt > CAP) cnt = CAP;
    float ce = 0.f;
    if (local < cnt) {
        int rr = rowlist[s];
        float l0 = logits2c[s * 2 + 0] + b2[e * 2 + 0];
        float l1 = logits2c[s * 2 + 1] + b2[e * 2 + 1];
        float mx = fmaxf(l0, l1);
        float e0 = expf(l0 - mx), e1 = expf(l1 - mx);
        float inv = 1.f / (e0 + e1);
        float p0 = e0 * inv, p1 = e1 * inv;
        float m2 = fmaxf(p0, p1);
        float z = m2 + logf(expf(p0 - m2) + expf(p1 - m2));
        float lp = ((label[rr] == 0) ? p0 : p1) - z;
        ce = -lp;
    }
    int lane = tid & 63, wave = tid >> 6;
    #pragma unroll
    for (int off = 32; off > 0; off >>= 1) ce += __shfl_xor(ce, off);
    if (lane == 0) red[wave] = ce;
    __syncthreads();
    if (tid == 0) atomicAdd(cesum, red[0] + red[1] + red[2] + red[3]);
}

// ---------------- finalize ----------------
__global__ void finalize_kernel(const float* __restrict__ S, const int* __restrict__ cursor,
                                const float* __restrict__ zsum, const float* __restrict__ cesum,
                                float* __restrict__ out)
{
    if (threadIdx.x == 0 && blockIdx.x == 0) {
        float bal = 0.f;
        for (int e = 0; e < NE; e++) bal += S[e] * (float)cursor[e];
        bal *= (float)NE / ((float)BQ * (float)BQ);
        out[0] = cesum[0] / (float)BQ + 0.01f * bal + 0.001f * (zsum[0] / (float)BQ);
    }
}

extern "C" void kernel_launch(void* const* d_in, const int* in_sizes, int n_in,
                              void* d_out, int out_size, void* d_ws, size_t ws_size,
                              hipStream_t stream) {
    const float* x      = (const float*)d_in[0];
    const int*   label  = (const int*)d_in[1];
    const float* gate_w = (const float*)d_in[2];
    const float* w1     = (const float*)d_in[3];
    const float* b1     = (const float*)d_in[4];
    const float* w2     = (const float*)d_in[5];
    const float* b2     = (const float*)d_in[6];
    float* out = (float*)d_out;

    char* ws = (char*)d_ws;
    int*   cursor   = (int*)(ws + WS_CURSOR);
    float* S        = (float*)(ws + WS_S);
    float* zsum     = (float*)(ws + WS_ZSUM);
    float* cesum    = (float*)(ws + WS_CESUM);
    int*   rowlist  = (int*)(ws + WS_ROWLIST);
    float* logits2c = (float*)(ws + WS_LOGITS2);
    unsigned short* xc  = (unsigned short*)(ws + WS_XC);
    unsigned short* w1t = (unsigned short*)(ws + WS_W1T);

    hipMemsetAsync(d_ws, 0, WS_HEAD, stream);

    prep_kernel<<<2560, 256, 0, stream>>>(x, gate_w, w1, cursor, S, zsum,
                                          rowlist, xc, w1t);
    expert_gemm_kernel<<<NE * NRT * NCT, 512, 0, stream>>>(xc, w1t, b1, w2,
                                                           cursor, logits2c);
    ce_kernel<<<NE * CAP / 256, 256, 0, stream>>>(logits2c, b2, cursor, rowlist,
                                                  label, cesum);
    finalize_kernel<<<1, 64, 0, stream>>>(S, cursor, zsum, cesum, out);
}

// Round 12
// 84.758 us; speedup vs baseline: 1.1996x; 1.1996x over previous
//
#include <hip/hip_runtime.h>
#include <math.h>

#define BQ 8192
#define HD 1024
#define NE 8
#define CAP 1280

#define BM 256
#define BN 128
#define BK 64            // fp8 elements per K-step (64 B rows, same geometry as R8)
#define NRT 5            // row tiles per expert (CAP/BM)
#define TILES_PER_E 40   // 8 col * 5 rt

// ---------------- workspace layout (bytes) ----------------
#define WS_CURSOR   0           // int[NE] (final == per-expert count)
#define WS_TICK     32          // int[NE] gemm work queue
#define WS_S        64          // float[NE]
#define WS_ZSUM     96          // float
#define WS_CESUM    100         // float
#define WS_ROWLIST  128         // int[NE*CAP] = 40960 -> ends 41088
#define WS_LOGITS2  41088       // float[NE*CAP*2] = 81920 -> ends 123008
#define WS_HEAD     123008      // memset size
#define WS_XC       123008      // fp8 xc [NE][CAP][HD] = 10485760 -> ends 10608768
#define WS_W1T      10608768    // fp8 w1^T*8 [NE][n][k] = 8388608

using f32x4  = __attribute__((ext_vector_type(4))) float;

__device__ __forceinline__ float gelu_exact(float v) {
    return 0.5f * v * (1.0f + erff(v * 0.70710678118654752440f));
}

// pack 4 floats -> 4 OCP e4m3 bytes (RNE, HW cvt)
__device__ __forceinline__ unsigned int f4_to_fp8x4(float f0, float f1, float f2, float f3) {
    int lo = __builtin_amdgcn_cvt_pk_fp8_f32(f0, f1, 0, false);
    return (unsigned int)__builtin_amdgcn_cvt_pk_fp8_f32(f2, f3, lo, true);
}

__device__ __forceinline__ void gll16(const void* g, void* l) {
    __builtin_amdgcn_global_load_lds((const __attribute__((address_space(1))) void*)g,
                                     (__attribute__((address_space(3))) void*)l, 16, 0, 0);
}

// ---- prep: router+compact (blocks 0..255) || w1 transpose (256..2303) -------
__global__ __launch_bounds__(256) void prep_kernel(
    const float* __restrict__ x, const float* __restrict__ gate_w,
    const float* __restrict__ w1,
    int* __restrict__ cursor, float* __restrict__ S, float* __restrict__ zsum,
    int* __restrict__ rowlist, unsigned char* __restrict__ xcq,
    unsigned char* __restrict__ w1tq)
{
    __shared__ __align__(16) char smem[33280];
    int tid = threadIdx.x;

    if (blockIdx.x >= 256) {
        // ---- transpose role: w1 fp32 [e][k][n] -> fp8 (x8) [e][n][k], 64x64 tile
        // lt[n][k] bytes, row pad 80 (16B aligned)
        char (*lt)[80] = (char (*)[80])smem;
        int tile = blockIdx.x - 256;          // 0..2047
        int e = tile >> 8;
        int rem = tile & 255;
        int k0 = (rem >> 4) << 6, n0 = (rem & 15) << 6;
        const float* src = w1 + ((size_t)e << 20) + (size_t)k0 * HD + n0;
        #pragma unroll
        for (int s = 0; s < 4; s++) {
            int q = tid + s * 256;
            int kk = q >> 4, n4 = q & 15;
            float4 v = *(const float4*)(src + (size_t)kk * HD + n4 * 4);
            unsigned int b = f4_to_fp8x4(v.x * 8.f, v.y * 8.f, v.z * 8.f, v.w * 8.f);
            lt[n4 * 4 + 0][kk] = (char)(b);
            lt[n4 * 4 + 1][kk] = (char)(b >> 8);
            lt[n4 * 4 + 2][kk] = (char)(b >> 16);
            lt[n4 * 4 + 3][kk] = (char)(b >> 24);
        }
        __syncthreads();
        int nn = tid >> 2, ch = tid & 3;
        unsigned char* dst = w1tq + ((size_t)e << 20) + (size_t)(n0 + nn) * HD + k0 + ch * 16;
        *(uint4*)dst = *(const uint4*)&lt[nn][ch * 16];
        return;
    }

    // ---- router role: rows [bid*32, bid*32+32)
    float* gw    = (float*)smem;                    // 32 KB
    float* sS    = (float*)(smem + 32768);          // 8
    float* sZ    = (float*)(smem + 32800);          // 1
    int*   sBI   = (int*)(smem + 32832);            // 32
    int*   sSlot = (int*)(smem + 32960);            // 32
    int*   sBase = (int*)(smem + 33088);            // 8

    for (int i = tid * 4; i < NE * HD; i += 256 * 4) {
        *(float4*)(gw + i) = *(const float4*)(gate_w + i);
    }
    if (tid < NE) sS[tid] = 0.f;
    if (tid == 0) sZ[0] = 0.f;
    __syncthreads();

    int wave = tid >> 6, lane = tid & 63;
    int r0 = blockIdx.x * 32;
    float accS[NE];
    #pragma unroll
    for (int e = 0; e < NE; e++) accS[e] = 0.f;
    float accZ = 0.f;

    // phase 1: logits + per-row argmax
    #pragma unroll 1
    for (int i = 0; i < 8; i++) {
        int li = wave * 8 + i;
        int r = r0 + li;
        const float* xr = x + (size_t)r * HD;
        float acc[NE];
        #pragma unroll
        for (int e = 0; e < NE; e++) acc[e] = 0.f;
        #pragma unroll
        for (int it = 0; it < 4; it++) {
            int k = lane * 4 + it * 256;
            float4 xv = *(const float4*)(xr + k);
            #pragma unroll
            for (int e = 0; e < NE; e++) {
                const float* g = gw + e * HD + k;
                acc[e] += xv.x * g[0] + xv.y * g[1] + xv.z * g[2] + xv.w * g[3];
            }
        }
        #pragma unroll
        for (int e = 0; e < NE; e++) {
            #pragma unroll
            for (int off = 32; off > 0; off >>= 1)
                acc[e] += __shfl_xor(acc[e], off);
        }
        if (lane == 0) {
            float m = acc[0]; int bi = 0;
            #pragma unroll
            for (int e = 1; e < NE; e++) if (acc[e] > m) { m = acc[e]; bi = e; }
            float se = 0.f, ex[NE];
            #pragma unroll
            for (int e = 0; e < NE; e++) { ex[e] = expf(acc[e] - m); se += ex[e]; }
            float inv = 1.f / se;
            #pragma unroll
            for (int e = 0; e < NE; e++) accS[e] += ex[e] * inv;
            float lse = m + logf(se);
            accZ += lse * lse;
            sBI[li] = bi;
        }
    }
    if (lane == 0) {
        #pragma unroll
        for (int e = 0; e < NE; e++) atomicAdd(&sS[e], accS[e]);
        atomicAdd(sZ, accZ);
    }
    __syncthreads();

    // phase 2: block-level capacity reservation (8 atomics per block)
    if (tid < NE) {
        int cnt = 0;
        #pragma unroll
        for (int j = 0; j < 32; j++) cnt += (sBI[j] == tid);
        sBase[tid] = atomicAdd(&cursor[tid], cnt);
        atomicAdd(&S[tid], sS[tid]);
    }
    if (tid == 0) atomicAdd(zsum, sZ[0]);
    __syncthreads();

    // phase 3: per-row slot = base + rank
    if (tid < 32) {
        int bi = sBI[tid];
        int rank = 0;
        for (int j = 0; j < tid; j++) rank += (sBI[j] == bi);
        int slot = sBase[bi] + rank;
        sSlot[tid] = slot;
        if (slot < CAP) rowlist[bi * CAP + slot] = r0 + tid;
    }
    __syncthreads();

    // phase 4: re-read (hot) x rows, convert fp8, write capacity slab
    #pragma unroll 1
    for (int i = 0; i < 8; i++) {
        int li = wave * 8 + i;
        int bi = sBI[li];
        int pos = sSlot[li];
        if (pos >= CAP) continue;
        const float* src = x + (size_t)(r0 + li) * HD + lane * 16;
        unsigned char* dst = xcq + ((size_t)(bi * CAP + pos)) * HD + lane * 16;
        float4 v0 = *(const float4*)(src + 0);
        float4 v1 = *(const float4*)(src + 4);
        float4 v2 = *(const float4*)(src + 8);
        float4 v3 = *(const float4*)(src + 12);
        uint4 o;
        o.x = f4_to_fp8x4(v0.x, v0.y, v0.z, v0.w);
        o.y = f4_to_fp8x4(v1.x, v1.y, v1.z, v1.w);
        o.z = f4_to_fp8x4(v2.x, v2.y, v2.z, v2.w);
        o.w = f4_to_fp8x4(v3.x, v3.y, v3.z, v3.w);
        *(uint4*)dst = o;
    }
}

// ---- MFMA expert GEMM (fp8): R8 skeleton, BK=64, 16 K-steps, 3-buf vmcnt(3) --
// grid 512 (2/CU), e = bid&7 (XCD-pinned). 512 thr = 8 waves (4x2), wave 64x64.
__global__ __launch_bounds__(512, 4) void expert_gemm_kernel(
    const unsigned char* __restrict__ xcq, const unsigned char* __restrict__ w1tq,
    const float* __restrict__ b1, const float* __restrict__ w2,
    const int* __restrict__ cursor, int* __restrict__ tick,
    float* __restrict__ logits2c)
{
    int e = blockIdx.x & 7;
    int cnt = cursor[e]; if (cnt > CAP) cnt = CAP;

    // 3 buffers x [A 16KB | B 8KB] = 72KB
    __shared__ __align__(16) char lds[3][24576];
    __shared__ int sTix;

    int t = threadIdx.x;
    int l = t & 63;
    // staging pre-swizzle (rule 21): chunk' = (t&3) ^ ((row>>1)&3), row = t>>2
    int scolb = ((t & 3) ^ ((t >> 3) & 3)) << 4;
    int m = t >> 2;                               // 0..127

    int wid = t >> 6;                 // 0..7
    int wr = wid >> 1, wc = wid & 1;  // 4 x 2 wave grid, wave tile 64x64
    int r = l & 15, h = l >> 4;       // frag row/col = r, k-quad = h
    // ds_read_b64 offsets for k-halves 0/1, chunk-XOR swizzled
    int swz = (r >> 1) & 3;
    int off0 = ((( (h >> 1)     ) ^ swz) << 4) | ((h & 1) * 8);   // kh=0: byte h*8
    int off1 = ((( (h >> 1) + 2 ) ^ swz) << 4) | ((h & 1) * 8);   // kh=1: byte 32+h*8

    const unsigned char* xcp  = xcq + ((size_t)e * CAP) * HD;
    const unsigned char* w1tp = w1tq + ((size_t)e << 20);

    for (;;) {
        if (t == 0) sTix = atomicAdd(&tick[e], 1);
        __syncthreads();                    // also: lds free from previous tile
        int tix = sTix;
        if (tix >= TILES_PER_E) break;
        int col = tix / NRT;                // consecutive pops share B panel
        int rt = tix - col * NRT;
        if (rt * BM >= cnt) continue;
        int n0 = col * BN;

        const unsigned char* srcA  = xcp + (size_t)(rt * BM + m) * HD + scolb;
        const unsigned char* srcA1 = srcA + (size_t)128 * HD;
        const unsigned char* srcB  = w1tp + (size_t)(n0 + m) * HD + scolb;

        f32x4 acc[4][4];
        #pragma unroll
        for (int i = 0; i < 4; i++)
            #pragma unroll
            for (int j = 0; j < 4; j++) acc[i][j] = (f32x4)(0.f);

        auto stage = [&](int bi) {
            gll16(srcA,  lds[bi] + t * 16);         srcA  += BK;
            gll16(srcA1, lds[bi] + 8192 + t * 16);  srcA1 += BK;
            gll16(srcB,  lds[bi] + 16384 + t * 16); srcB  += BK;
        };
        auto compute = [&](int bi) {
            const char* Ar = lds[bi] + (wr * 64 + r) * 64;
            const char* Br = lds[bi] + 16384 + (wc * 64 + r) * 64;
            long a0[4], a1[4], b0[4], b1r[4];
            #pragma unroll
            for (int i = 0; i < 4; i++) {
                a0[i]  = *(const long*)(Ar + i * 1024 + off0);
                a1[i]  = *(const long*)(Ar + i * 1024 + off1);
                b0[i]  = *(const long*)(Br + i * 1024 + off0);
                b1r[i] = *(const long*)(Br + i * 1024 + off1);
            }
            #pragma unroll
            for (int i = 0; i < 4; i++)
                #pragma unroll
                for (int j = 0; j < 4; j++)
                    acc[i][j] = __builtin_amdgcn_mfma_f32_16x16x32_fp8_fp8(a0[i], b0[j], acc[i][j], 0, 0, 0);
            #pragma unroll
            for (int i = 0; i < 4; i++)
                #pragma unroll
                for (int j = 0; j < 4; j++)
                    acc[i][j] = __builtin_amdgcn_mfma_f32_16x16x32_fp8_fp8(a1[i], b1r[j], acc[i][j], 0, 0, 0);
        };

        stage(0); stage(1);
        int cs = 2, cc = 0;
        #pragma unroll 1
        for (int it = 0; it < HD / BK - 2; ++it) {
            asm volatile("s_waitcnt vmcnt(3)" ::: "memory");
            __builtin_amdgcn_s_barrier();
            stage(cs); cs = (cs == 2) ? 0 : cs + 1;
            compute(cc); cc = (cc == 2) ? 0 : cc + 1;
        }
        asm volatile("s_waitcnt vmcnt(3)" ::: "memory");
        __builtin_amdgcn_s_barrier();
        compute(cc); cc = (cc == 2) ? 0 : cc + 1;
        asm volatile("s_waitcnt vmcnt(0)" ::: "memory");
        __builtin_amdgcn_s_barrier();
        compute(cc);

        // epilogue: descale (w1 was x8) + bias + gelu + w2 dot + 16-lane reduce
        float b1v[4], w20v[4], w21v[4];
        #pragma unroll
        for (int j = 0; j < 4; j++) {
            int cj = n0 + wc * 64 + j * 16 + r;
            b1v[j]  = b1[e * HD + cj];
            w20v[j] = w2[((size_t)e * HD + cj) * 2 + 0];
            w21v[j] = w2[((size_t)e * HD + cj) * 2 + 1];
        }
        #pragma unroll
        for (int i = 0; i < 4; i++) {
            #pragma unroll
            for (int reg = 0; reg < 4; reg++) {
                float s0 = 0.f, s1 = 0.f;
                #pragma unroll
                for (int j = 0; j < 4; j++) {
                    float hv = gelu_exact(acc[i][j][reg] * 0.125f + b1v[j]);
                    s0 += hv * w20v[j];
                    s1 += hv * w21v[j];
                }
                #pragma unroll
                for (int offx = 1; offx < 16; offx <<= 1) {
                    s0 += __shfl_xor(s0, offx);
                    s1 += __shfl_xor(s1, offx);
                }
                if (r == 0) {
                    int lm = wr * 64 + i * 16 + 4 * h + reg;
                    int p = rt * BM + lm;
                    if (p < cnt) {
                        atomicAdd(&logits2c[(e * CAP + p) * 2 + 0], s0);
                        atomicAdd(&logits2c[(e * CAP + p) * 2 + 1], s1);
                    }
                }
            }
        }
    }
}

// ---- CE over (softmaxed) expert outputs (capacity-slot order) ---------------
__global__ __launch_bounds__(256) void ce_kernel(
    const float* __restrict__ logits2c, const float* __restrict__ b2,
    const int* __restrict__ cursor, const int* __restrict__ rowlist,
    const int* __restrict__ label, float* __restrict__ cesum)
{
    __shared__ float red[4];
    int tid = threadIdx.x;
    int s = blockIdx.x * 256 + tid;     // 0..NE*CAP-1
    int e = s / CAP;
    int local = s - e * CAP;
    int cnt = cursor[e]; if (cnt > CAP) cnt = CAP;
    float ce = 0.f;
    if (local < cnt) {
        int rr = rowlist[s];
        float l0 = logits2c[s * 2 + 0] + b2[e * 2 + 0];
        float l1 = logits2c[s * 2 + 1] + b2[e * 2 + 1];
        float mx = fmaxf(l0, l1);
        float e0 = expf(l0 - mx), e1 = expf(l1 - mx);
        float inv = 1.f / (e0 + e1);
        float p0 = e0 * inv, p1 = e1 * inv;
        float m2 = fmaxf(p0, p1);
        float z = m2 + logf(expf(p0 - m2) + expf(p1 - m2));
        float lp = ((label[rr] == 0) ? p0 : p1) - z;
        ce = -lp;
    }
    int lane = tid & 63, wave = tid >> 6;
    #pragma unroll
    for (int off = 32; off > 0; off >>= 1) ce += __shfl_xor(ce, off);
    if (lane == 0) red[wave] = ce;
    __syncthreads();
    if (tid == 0) atomicAdd(cesum, red[0] + red[1] + red[2] + red[3]);
}

// ---------------- finalize ----------------
__global__ void finalize_kernel(const float* __restrict__ S, const int* __restrict__ cursor,
                                const float* __restrict__ zsum, const float* __restrict__ cesum,
                                float* __restrict__ out)
{
    if (threadIdx.x == 0 && blockIdx.x == 0) {
        float bal = 0.f;
        for (int e = 0; e < NE; e++) bal += S[e] * (float)cursor[e];
        bal *= (float)NE / ((float)BQ * (float)BQ);
        out[0] = cesum[0] / (float)BQ + 0.01f * bal + 0.001f * (zsum[0] / (float)BQ);
    }
}

extern "C" void kernel_launch(void* const* d_in, const int* in_sizes, int n_in,
                              void* d_out, int out_size, void* d_ws, size_t ws_size,
                              hipStream_t stream) {
    const float* x      = (const float*)d_in[0];
    const int*   label  = (const int*)d_in[1];
    const float* gate_w = (const float*)d_in[2];
    const float* w1     = (const float*)d_in[3];
    const float* b1     = (const float*)d_in[4];
    const float* w2     = (const float*)d_in[5];
    const float* b2     = (const float*)d_in[6];
    float* out = (float*)d_out;

    char* ws = (char*)d_ws;
    int*   cursor   = (int*)(ws + WS_CURSOR);
    int*   tick     = (int*)(ws + WS_TICK);
    float* S        = (float*)(ws + WS_S);
    float* zsum     = (float*)(ws + WS_ZSUM);
    float* cesum    = (float*)(ws + WS_CESUM);
    int*   rowlist  = (int*)(ws + WS_ROWLIST);
    float* logits2c = (float*)(ws + WS_LOGITS2);
    unsigned char* xcq  = (unsigned char*)(ws + WS_XC);
    unsigned char* w1tq = (unsigned char*)(ws + WS_W1T);

    hipMemsetAsync(d_ws, 0, WS_HEAD, stream);

    prep_kernel<<<2304, 256, 0, stream>>>(x, gate_w, w1, cursor, S, zsum,
                                          rowlist, xcq, w1tq);
    expert_gemm_kernel<<<512, 512, 0, stream>>>(xcq, w1tq, b1, w2, cursor, tick,
                                                logits2c);
    ce_kernel<<<NE * CAP / 256, 256, 0, stream>>>(logits2c, b2, cursor, rowlist,
                                                  label, cesum);
    finalize_kernel<<<1, 64, 0, stream>>>(S, cursor, zsum, cesum, out);
}